// Round 1
// baseline (339.467 us; speedup 1.0000x reference)
//
#include <hip/hip_runtime.h>
#include <stdint.h>

typedef unsigned short u16;
typedef __attribute__((ext_vector_type(8))) short bf16x8;
typedef __attribute__((ext_vector_type(4))) float f32x4;

#define NB 32
#define CH 512
#define HH 28
#define HP 30
#define KTOT 4608   // 9*512
#define BM 128
#define BN 112
#define BK 64
#define ASZ (BM*BK)   // 8192 u16
#define BSZ (BN*BK)   // 7168 u16
#define KSTEPS 72     // 4608/64

__device__ __forceinline__ u16 f2bf(float f) {
    uint32_t u = __float_as_uint(f);
    uint32_t r = (u + 0x7fffu + ((u >> 16) & 1u)) >> 16;
    return (u16)r;
}

// ---------------- kernel 1: per-(b,c) centroid stats ----------------
__global__ __launch_bounds__(256) void stats_kernel(
    const float* __restrict__ x, float* __restrict__ muX, float* __restrict__ muY)
{
    int pair = blockIdx.x * 4 + (threadIdx.x >> 6);   // b*512 + c
    int lane = threadIdx.x & 63;
    const float* xp = x + (size_t)pair * 784;
    float s = 0.f, sx = 0.f, sy = 0.f;
    for (int e = lane; e < 784; e += 64) {
        float v = xp[e];
        int i = e / 28, j = e - i * 28;
        s += v;
        sx += (float)(i + 1) * v;
        sy += (float)(j + 1) * v;
    }
    #pragma unroll
    for (int off = 32; off > 0; off >>= 1) {
        s  += __shfl_down(s, off);
        sx += __shfl_down(sx, off);
        sy += __shfl_down(sy, off);
    }
    if (lane == 0) {
        float S = fmaxf(s, 1e-9f);
        float mx = fmaxf(rintf(sx / S), 1.0f);
        float my = fmaxf(rintf(sy / S), 1.0f);
        int ix = (int)(mx - 1.0f); if (ix > 27) ix = 27;
        int iy = (int)(my - 1.0f); if (iy > 27) iy = 27;
        muX[pair] = -1.0f + (2.0f / 27.0f) * (float)ix;
        muY[pair] = -1.0f + (2.0f / 27.0f) * (float)iy;
    }
}

// ------- kernel 2: mask+relu, NCHW f32 -> padded NHWC bf16 ----------
// one block per (b, row i); interior of xr_pad[b][i+1][1..28][c]
__global__ __launch_bounds__(256) void mask_relu_transpose(
    const float* __restrict__ x, const float* __restrict__ mw,
    const float* __restrict__ filt, const float* __restrict__ muX,
    const float* __restrict__ muY, u16* __restrict__ xr_pad)
{
    __shared__ u16 tile[CH * 28];   // [c][j]
    int bid = blockIdx.x;
    int b = bid / 28, i = bid - (bid / 28) * 28;
    int tid = threadIdx.x;
    float px = -1.0f + (2.0f / 27.0f) * (float)i;
    const float* xb = x + (size_t)b * CH * 784 + i * 28;
    const float* muXb = muX + b * CH;
    const float* muYb = muY + b * CH;
    #pragma unroll 8
    for (int k = 0; k < 56; ++k) {
        int e = tid + k * 256;          // e = c*28 + j
        int c = e / 28, j = e - c * 28;
        float v = xb[c * 784 + j];
        float py = -1.0f + (2.0f / 27.0f) * (float)j;
        float m = 1.0f - (fabsf(px - muXb[c]) + fabsf(py - muYb[c])) * mw[c];
        m = fmaxf(m, -1.0f);
        if (filt[c] != 1.0f) m = 1.0f;
        v = fmaxf(v * m, 0.0f);
        tile[e] = f2bf(v);
    }
    __syncthreads();
    u16* outb = xr_pad + (((size_t)b * HP + (i + 1)) * HP + 1) * CH;
    #pragma unroll
    for (int k = 0; k < 7; ++k) {
        int ch = tid + k * 256;         // 1792 chunks of 8 channels
        int j = ch >> 6;
        int c0 = (ch & 63) << 3;
        __align__(16) u16 vals[8];
        #pragma unroll
        for (int q = 0; q < 8; ++q) vals[q] = tile[(c0 + q) * 28 + j];
        *reinterpret_cast<uint4*>(outb + (size_t)j * CH + c0) =
            *reinterpret_cast<const uint4*>(vals);
    }
}

// ------- kernel 3: weight reorder: w[oc][ic][t] -> bf16 w_r[oc][t*512+ic]
__global__ __launch_bounds__(256) void weight_reorder(
    const float* __restrict__ w, u16* __restrict__ w_r)
{
    int o0 = (blockIdx.x * 256 + threadIdx.x) * 8;
    if (o0 >= CH * KTOT) return;
    int oc = o0 / KTOT;
    int rem = o0 - oc * KTOT;
    int t = rem / 512;
    int ic0 = rem - t * 512;
    __align__(16) u16 vals[8];
    #pragma unroll
    for (int q = 0; q < 8; ++q)
        vals[q] = f2bf(w[(size_t)oc * KTOT + (ic0 + q) * 9 + t]);
    *reinterpret_cast<uint4*>(w_r + o0) = *reinterpret_cast<const uint4*>(vals);
}

// ------- kernel 4: implicit-GEMM conv, bf16 MFMA ----------
// grid: 32 batches * 4 mtiles * 7 ntiles = 896 blocks, 256 threads (4 waves)
__global__ __launch_bounds__(256, 2) void conv_gemm(
    const u16* __restrict__ w_r, const u16* __restrict__ xr_pad,
    const float* __restrict__ bias, float* __restrict__ out)
{
    __shared__ __align__(16) u16 smem[2][ASZ + BSZ];
    int bid = blockIdx.x;
    int b = bid / 28;
    int rem = bid - b * 28;
    int m0 = (rem / 7) * BM;
    int n0 = (rem - (rem / 7) * 7) * BN;
    int tid = threadIdx.x;
    int lane = tid & 63;
    int wv = tid >> 6;

    // --- precompute per-thread staging addresses (element offsets) ---
    uint32_t aoff[4], boff[4], ldsoffA[4], ldsoffB[4];
    #pragma unroll
    for (int it = 0; it < 4; ++it) {
        int c = tid * 16 + it * 4096;          // byte offset in A tile (16KB)
        int row = c >> 7;                       // 128B per row
        aoff[it] = (uint32_t)(m0 + row) * KTOT + ((c & 127) >> 1);
        ldsoffA[it] = c >> 1;
        int nl = c >> 7;                        // row in B tile
        int n = n0 + (nl < BN ? nl : 0);
        int oh = n / 28, ow = n - oh * 28;
        boff[it] = (uint32_t)(((b * HP + oh) * HP + ow) * CH) + ((c & 127) >> 1);
        ldsoffB[it] = c >> 1;
    }

    auto stage = [&](int buf, int ks) {
        u16* sA = &smem[buf][0];
        u16* sB = &smem[buf][ASZ];
        int koff = ks * 64;
        #pragma unroll
        for (int it = 0; it < 4; ++it) {
            __builtin_amdgcn_global_load_lds(
                (const __attribute__((address_space(1))) uint32_t*)(w_r + aoff[it] + koff),
                (__attribute__((address_space(3))) uint32_t*)(sA + ldsoffA[it]),
                16, 0, 0);
        }
        int tap = ks >> 3;                 // 0..8
        int kh = tap / 3, kw = tap - kh * 3;
        int xoff = (kh * HP + kw) * CH + (ks & 7) * 64;
        #pragma unroll
        for (int it = 0; it < 4; ++it) {
            if (tid * 16 + it * 4096 < BSZ * 2) {   // B tile is 14336 bytes
                __builtin_amdgcn_global_load_lds(
                    (const __attribute__((address_space(1))) uint32_t*)(xr_pad + boff[it] + xoff),
                    (__attribute__((address_space(3))) uint32_t*)(sB + ldsoffB[it]),
                    16, 0, 0);
            }
        }
    };

    f32x4 acc[2][7];
    #pragma unroll
    for (int mi = 0; mi < 2; ++mi)
        #pragma unroll
        for (int ni = 0; ni < 7; ++ni)
            acc[mi][ni] = (f32x4){0.f, 0.f, 0.f, 0.f};

    int r15 = lane & 15;
    int rq = lane >> 4;

    stage(0, 0);
    for (int ks = 0; ks < KSTEPS; ++ks) {
        __syncthreads();                       // drains vmcnt: tile ks ready
        if (ks + 1 < KSTEPS) stage((ks + 1) & 1, ks + 1);
        const u16* sA = &smem[ks & 1][0];
        const u16* sB = &smem[ks & 1][ASZ];
        #pragma unroll
        for (int kk = 0; kk < 2; ++kk) {
            bf16x8 a0 = *reinterpret_cast<const bf16x8*>(sA + (wv * 32 + r15) * BK + kk * 32 + rq * 8);
            bf16x8 a1 = *reinterpret_cast<const bf16x8*>(sA + (wv * 32 + 16 + r15) * BK + kk * 32 + rq * 8);
            #pragma unroll
            for (int ni = 0; ni < 7; ++ni) {
                bf16x8 bv = *reinterpret_cast<const bf16x8*>(sB + (ni * 16 + r15) * BK + kk * 32 + rq * 8);
                acc[0][ni] = __builtin_amdgcn_mfma_f32_16x16x32_bf16(a0, bv, acc[0][ni], 0, 0, 0);
                acc[1][ni] = __builtin_amdgcn_mfma_f32_16x16x32_bf16(a1, bv, acc[1][ni], 0, 0, 0);
            }
        }
    }

    // epilogue: D row=(lane>>4)*4+r, col=lane&15 ; add bias, write NCHW f32
    float* outb = out + (size_t)b * CH * 784;
    #pragma unroll
    for (int mi = 0; mi < 2; ++mi) {
        #pragma unroll
        for (int ni = 0; ni < 7; ++ni) {
            f32x4 v = acc[mi][ni];
            int row0 = m0 + wv * 32 + mi * 16 + rq * 4;
            int col = n0 + ni * 16 + r15;
            #pragma unroll
            for (int r = 0; r < 4; ++r) {
                int row = row0 + r;
                outb[(size_t)row * 784 + col] = v[r] + bias[row];
            }
        }
    }
}

extern "C" void kernel_launch(void* const* d_in, const int* in_sizes, int n_in,
                              void* d_out, int out_size, void* d_ws, size_t ws_size,
                              hipStream_t stream)
{
    const float* x    = (const float*)d_in[0];
    const float* wgt  = (const float*)d_in[1];
    const float* bias = (const float*)d_in[2];
    const float* mw   = (const float*)d_in[3];
    const float* filt = (const float*)d_in[4];
    // d_in[5] = padding (==1, hardcoded)

    const size_t XR_BYTES = (size_t)NB * HP * HP * CH * 2;   // 29,491,200
    const size_t WR_BYTES = (size_t)CH * KTOT * 2;           //  4,718,592
    u16* xr_pad = (u16*)d_ws;
    u16* w_r    = (u16*)((char*)d_ws + XR_BYTES);
    float* muX  = (float*)((char*)d_ws + XR_BYTES + WR_BYTES);
    float* muY  = (float*)((char*)d_ws + XR_BYTES + WR_BYTES + 65536);

    hipMemsetAsync(xr_pad, 0, XR_BYTES, stream);
    hipLaunchKernelGGL(stats_kernel, dim3(4096), dim3(256), 0, stream, x, muX, muY);
    hipLaunchKernelGGL(mask_relu_transpose, dim3(NB * 28), dim3(256), 0, stream,
                       x, mw, filt, muX, muY, xr_pad);
    hipLaunchKernelGGL(weight_reorder, dim3(1152), dim3(256), 0, stream, wgt, w_r);
    hipLaunchKernelGGL(conv_gemm, dim3(NB * 4 * 7), dim3(256), 0, stream,
                       w_r, xr_pad, bias, (float*)d_out);
}

// Round 2
// 265.573 us; speedup vs baseline: 1.2782x; 1.2782x over previous
//
#include <hip/hip_runtime.h>
#include <stdint.h>

typedef unsigned short u16;
typedef __attribute__((ext_vector_type(8))) short bf16x8;
typedef __attribute__((ext_vector_type(4))) float f32x4;

#define NB 32
#define CH 512
#define HH 28
#define HP 30
#define KTOT 4608   // 9*512
#define BM 128
#define BN 112
#define BK 64
#define ASZ (BM*BK)   // 8192 u16
#define BSZ (BN*BK)   // 7168 u16
#define KSTEPS 72     // 4608/64

__device__ __forceinline__ u16 f2bf(float f) {
    uint32_t u = __float_as_uint(f);
    uint32_t r = (u + 0x7fffu + ((u >> 16) & 1u)) >> 16;
    return (u16)r;
}

// ---------------- kernel 1: per-(b,c) centroid stats ----------------
__global__ __launch_bounds__(256) void stats_kernel(
    const float* __restrict__ x, float* __restrict__ muX, float* __restrict__ muY)
{
    int pair = blockIdx.x * 4 + (threadIdx.x >> 6);   // b*512 + c
    int lane = threadIdx.x & 63;
    const float* xp = x + (size_t)pair * 784;
    float s = 0.f, sx = 0.f, sy = 0.f;
    for (int e = lane; e < 784; e += 64) {
        float v = xp[e];
        int i = e / 28, j = e - i * 28;
        s += v;
        sx += (float)(i + 1) * v;
        sy += (float)(j + 1) * v;
    }
    #pragma unroll
    for (int off = 32; off > 0; off >>= 1) {
        s  += __shfl_down(s, off);
        sx += __shfl_down(sx, off);
        sy += __shfl_down(sy, off);
    }
    if (lane == 0) {
        float S = fmaxf(s, 1e-9f);
        float mx = fmaxf(rintf(sx / S), 1.0f);
        float my = fmaxf(rintf(sy / S), 1.0f);
        int ix = (int)(mx - 1.0f); if (ix > 27) ix = 27;
        int iy = (int)(my - 1.0f); if (iy > 27) iy = 27;
        muX[pair] = -1.0f + (2.0f / 27.0f) * (float)ix;
        muY[pair] = -1.0f + (2.0f / 27.0f) * (float)iy;
    }
}

// ------- kernel 2: mask+relu, NCHW f32 -> padded NHWC bf16 ----------
// one block per (b, row i); interior of xr_pad[b][i+1][1..28][c]
// LDS layout [j][c] with stride 520: phase-2 reads are contiguous b128.
#define TSTR 520
__global__ __launch_bounds__(256) void mask_relu_transpose(
    const float* __restrict__ x, const float* __restrict__ mw,
    const float* __restrict__ filt, const float* __restrict__ muX,
    const float* __restrict__ muY, u16* __restrict__ xr_pad)
{
    __shared__ u16 tile[28 * TSTR];   // [j][c], 29120 B
    int bid = blockIdx.x;
    int b = bid / 28, i = bid - (bid / 28) * 28;
    int tid = threadIdx.x;
    float px = -1.0f + (2.0f / 27.0f) * (float)i;
    const float* xb = x + (size_t)b * CH * 784 + i * 28;
    const float* muXb = muX + b * CH;
    const float* muYb = muY + b * CH;
    #pragma unroll 8
    for (int k = 0; k < 56; ++k) {
        int e = tid + k * 256;          // e = c*28 + j  (coalesced global read)
        int c = e / 28, j = e - c * 28;
        float v = xb[c * 784 + j];
        float py = -1.0f + (2.0f / 27.0f) * (float)j;
        float m = 1.0f - (fabsf(px - muXb[c]) + fabsf(py - muYb[c])) * mw[c];
        m = fmaxf(m, -1.0f);
        if (filt[c] != 1.0f) m = 1.0f;
        tile[j * TSTR + c] = f2bf(fmaxf(v * m, 0.0f));
    }
    __syncthreads();
    u16* outb = xr_pad + (((size_t)b * HP + (i + 1)) * HP + 1) * CH;
    #pragma unroll
    for (int k = 0; k < 7; ++k) {
        int ch = tid + k * 256;         // 1792 chunks of 8 channels
        int j = ch >> 6;
        int c0 = (ch & 63) << 3;
        *reinterpret_cast<uint4*>(outb + (size_t)j * CH + c0) =
            *reinterpret_cast<const uint4*>(&tile[j * TSTR + c0]);
    }
}

// ------- kernel 3: weight reorder: w[oc][ic*9+t] -> bf16 w_r[oc][t*512+ic]
// one block per oc: transposed LDS write, contiguous vector read+store.
__global__ __launch_bounds__(256) void weight_reorder(
    const float* __restrict__ w, u16* __restrict__ w_r)
{
    __shared__ u16 t[KTOT];
    int oc = blockIdx.x;
    const float* wrow = w + (size_t)oc * KTOT;
    int tid = threadIdx.x;
    #pragma unroll
    for (int k = 0; k < 18; ++k) {
        int idx = tid + k * 256;        // idx = ic*9 + tap (coalesced global read)
        int ic = idx / 9, tap = idx - ic * 9;
        t[tap * 512 + ic] = f2bf(wrow[idx]);
    }
    __syncthreads();
    u16* dst = w_r + (size_t)oc * KTOT;
    #pragma unroll
    for (int k = 0; k < 3; ++k) {
        int ch = tid + k * 256;
        if (ch < 576)
            *reinterpret_cast<uint4*>(dst + ch * 8) =
                *reinterpret_cast<const uint4*>(&t[ch * 8]);
    }
}

// ------- kernel 4: implicit-GEMM conv, bf16 MFMA, swizzled LDS ----------
// grid: 896 blocks (XCD-contiguous remap), 256 threads (4 waves)
__global__ __launch_bounds__(256, 2) void conv_gemm(
    const u16* __restrict__ w_r, const u16* __restrict__ xr_pad,
    const float* __restrict__ bias, float* __restrict__ out)
{
    __shared__ __align__(16) u16 smem[2][ASZ + BSZ];
    int p = blockIdx.x;
    int bid = (p & 7) * 112 + (p >> 3);     // T1: each XCD gets 4 contiguous batches
    int b = bid / 28;
    int rem = bid - b * 28;
    int m0 = (rem / 7) * BM;
    int n0 = (rem - (rem / 7) * 7) * BN;
    int tid = threadIdx.x;
    int lane = tid & 63;
    int wv = tid >> 6;

    // --- staging addresses; T2 swizzle baked into the GLOBAL source column ---
    uint32_t aoff[4], boff[4], ldsoff[4];
    #pragma unroll
    for (int it = 0; it < 4; ++it) {
        int c = tid * 16 + it * 4096;           // byte offset in tile
        int row = c >> 7;                        // 128B per row
        int scol = (c & 127) ^ ((row & 7) << 4); // inverse-swizzled source column
        aoff[it] = (uint32_t)(m0 + row) * KTOT + (scol >> 1);
        ldsoff[it] = c >> 1;                     // LDS dest stays LINEAR
        int n = n0 + (row < BN ? row : 0);
        int oh = n / 28, ow = n - oh * 28;
        boff[it] = (uint32_t)(((b * HP + oh) * HP + ow) * CH) + (scol >> 1);
    }

    auto stage = [&](int buf, int ks) {
        u16* sA = &smem[buf][0];
        u16* sB = &smem[buf][ASZ];
        int koff = ks * 64;
        #pragma unroll
        for (int it = 0; it < 4; ++it) {
            __builtin_amdgcn_global_load_lds(
                (const __attribute__((address_space(1))) uint32_t*)(w_r + aoff[it] + koff),
                (__attribute__((address_space(3))) uint32_t*)(sA + ldsoff[it]),
                16, 0, 0);
        }
        int tap = ks >> 3;                 // 0..8
        int kh = tap / 3, kw = tap - kh * 3;
        int xoff = (kh * HP + kw) * CH + (ks & 7) * 64;
        #pragma unroll
        for (int it = 0; it < 4; ++it) {
            if (tid * 16 + it * 4096 < BSZ * 2) {
                __builtin_amdgcn_global_load_lds(
                    (const __attribute__((address_space(1))) uint32_t*)(xr_pad + boff[it] + xoff),
                    (__attribute__((address_space(3))) uint32_t*)(sB + ldsoff[it]),
                    16, 0, 0);
            }
        }
    };

    f32x4 acc[2][7];
    #pragma unroll
    for (int mi = 0; mi < 2; ++mi)
        #pragma unroll
        for (int ni = 0; ni < 7; ++ni)
            acc[mi][ni] = (f32x4){0.f, 0.f, 0.f, 0.f};

    int r15 = lane & 15;
    int rq = lane >> 4;
    // swizzled read offsets (loop-invariant, in u16 elements)
    int xorv = (r15 & 7) << 4;                  // byte XOR, row&7 == r15&7 everywhere
    int cb0 = (((rq * 16)      ) ^ xorv) >> 1;  // kk=0 column
    int cb1 = (((rq * 16) + 64 ) ^ xorv) >> 1;  // kk=1 column
    int arow = (wv * 32 + r15) * BK;
    int brow = r15 * BK;

    stage(0, 0);
    for (int ks = 0; ks < KSTEPS; ++ks) {
        __syncthreads();                       // drains vmcnt: tile ks ready
        if (ks + 1 < KSTEPS) stage((ks + 1) & 1, ks + 1);
        const u16* sA = &smem[ks & 1][0];
        const u16* sB = &smem[ks & 1][ASZ];
        #pragma unroll
        for (int kk = 0; kk < 2; ++kk) {
            int cb = kk ? cb1 : cb0;
            bf16x8 a0 = *reinterpret_cast<const bf16x8*>(sA + arow + cb);
            bf16x8 a1 = *reinterpret_cast<const bf16x8*>(sA + arow + 1024 + cb);
            #pragma unroll
            for (int ni = 0; ni < 7; ++ni) {
                bf16x8 bv = *reinterpret_cast<const bf16x8*>(sB + brow + ni * 1024 + cb);
                acc[0][ni] = __builtin_amdgcn_mfma_f32_16x16x32_bf16(a0, bv, acc[0][ni], 0, 0, 0);
                acc[1][ni] = __builtin_amdgcn_mfma_f32_16x16x32_bf16(a1, bv, acc[1][ni], 0, 0, 0);
            }
        }
    }

    // epilogue: D row=(lane>>4)*4+r, col=lane&15 ; add bias, write NCHW f32
    float* outb = out + (size_t)b * CH * 784;
    #pragma unroll
    for (int mi = 0; mi < 2; ++mi) {
        #pragma unroll
        for (int ni = 0; ni < 7; ++ni) {
            f32x4 v = acc[mi][ni];
            int row0 = m0 + wv * 32 + mi * 16 + rq * 4;
            int col = n0 + ni * 16 + r15;
            #pragma unroll
            for (int r = 0; r < 4; ++r) {
                int row = row0 + r;
                outb[(size_t)row * 784 + col] = v[r] + bias[row];
            }
        }
    }
}

extern "C" void kernel_launch(void* const* d_in, const int* in_sizes, int n_in,
                              void* d_out, int out_size, void* d_ws, size_t ws_size,
                              hipStream_t stream)
{
    const float* x    = (const float*)d_in[0];
    const float* wgt  = (const float*)d_in[1];
    const float* bias = (const float*)d_in[2];
    const float* mw   = (const float*)d_in[3];
    const float* filt = (const float*)d_in[4];
    // d_in[5] = padding (==1, hardcoded)

    const size_t XR_BYTES = (size_t)NB * HP * HP * CH * 2;   // 29,491,200
    const size_t WR_BYTES = (size_t)CH * KTOT * 2;           //  4,718,592
    u16* xr_pad = (u16*)d_ws;
    u16* w_r    = (u16*)((char*)d_ws + XR_BYTES);
    float* muX  = (float*)((char*)d_ws + XR_BYTES + WR_BYTES);
    float* muY  = (float*)((char*)d_ws + XR_BYTES + WR_BYTES + 65536);

    hipMemsetAsync(xr_pad, 0, XR_BYTES, stream);
    hipLaunchKernelGGL(stats_kernel, dim3(4096), dim3(256), 0, stream, x, muX, muY);
    hipLaunchKernelGGL(mask_relu_transpose, dim3(NB * 28), dim3(256), 0, stream,
                       x, mw, filt, muX, muY, xr_pad);
    hipLaunchKernelGGL(weight_reorder, dim3(512), dim3(256), 0, stream, wgt, w_r);
    hipLaunchKernelGGL(conv_gemm, dim3(NB * 4 * 7), dim3(256), 0, stream,
                       w_r, xr_pad, bias, (float*)d_out);
}

// Round 6
// 248.743 us; speedup vs baseline: 1.3647x; 1.0677x over previous
//
#include <hip/hip_runtime.h>
#include <stdint.h>

typedef unsigned short u16;
typedef __attribute__((ext_vector_type(8))) short bf16x8;
typedef __attribute__((ext_vector_type(4))) float f32x4;

#define NB 32
#define CH 512
#define HP 30
#define KTOT 4608         // 9*512
#define BM 256
#define BN 224
#define BK 64
#define ABYTES 32768      // BM*BK*2
#define BBYTES 28672      // BN*BK*2
#define BUFU16 30720      // (ABYTES+BBYTES)/2
#define KSTEPS 72         // 4608/64

__device__ __forceinline__ u16 f2bf(float f) {
    uint32_t u = __float_as_uint(f);
    uint32_t r = (u + 0x7fffu + ((u >> 16) & 1u)) >> 16;
    return (u16)r;
}

// ---------------- kernel 1: per-(b,c) centroid stats (round-2 proven) ----
__global__ __launch_bounds__(256) void stats_kernel(
    const float* __restrict__ x, float* __restrict__ muX, float* __restrict__ muY)
{
    int pair = blockIdx.x * 4 + (threadIdx.x >> 6);   // b*512 + c
    int lane = threadIdx.x & 63;
    const float* xp = x + (size_t)pair * 784;
    float s = 0.f, sx = 0.f, sy = 0.f;
    for (int e = lane; e < 784; e += 64) {
        float v = xp[e];
        int i = e / 28, j = e - i * 28;
        s += v;
        sx += (float)(i + 1) * v;
        sy += (float)(j + 1) * v;
    }
    #pragma unroll
    for (int off = 32; off > 0; off >>= 1) {
        s  += __shfl_down(s, off);
        sx += __shfl_down(sx, off);
        sy += __shfl_down(sy, off);
    }
    if (lane == 0) {
        float S = fmaxf(s, 1e-9f);
        float mx = fmaxf(rintf(sx / S), 1.0f);
        float my = fmaxf(rintf(sy / S), 1.0f);
        int ix = (int)(mx - 1.0f); if (ix > 27) ix = 27;
        int iy = (int)(my - 1.0f); if (iy > 27) iy = 27;
        muX[pair] = -1.0f + (2.0f / 27.0f) * (float)ix;
        muY[pair] = -1.0f + (2.0f / 27.0f) * (float)iy;
    }
}

// ------- kernel 2: mask+relu transpose (round-2 proven) ----------
#define TSTR 520
__global__ __launch_bounds__(256) void mask_relu_transpose(
    const float* __restrict__ x, const float* __restrict__ mw,
    const float* __restrict__ filt, const float* __restrict__ muX,
    const float* __restrict__ muY, u16* __restrict__ xr_pad)
{
    __shared__ u16 tile[28 * TSTR];   // [j][c]
    int bid = blockIdx.x;
    int b = bid / 28, i = bid - (bid / 28) * 28;
    int tid = threadIdx.x;
    float px = -1.0f + (2.0f / 27.0f) * (float)i;
    const float* xb = x + (size_t)b * CH * 784 + i * 28;
    const float* muXb = muX + b * CH;
    const float* muYb = muY + b * CH;
    #pragma unroll 8
    for (int k = 0; k < 56; ++k) {
        int e = tid + k * 256;          // e = c*28 + j  (coalesced global read)
        int c = e / 28, j = e - c * 28;
        float v = xb[c * 784 + j];
        float py = -1.0f + (2.0f / 27.0f) * (float)j;
        float m = 1.0f - (fabsf(px - muXb[c]) + fabsf(py - muYb[c])) * mw[c];
        m = fmaxf(m, -1.0f);
        if (filt[c] != 1.0f) m = 1.0f;
        tile[j * TSTR + c] = f2bf(fmaxf(v * m, 0.0f));
    }
    __syncthreads();
    u16* outb = xr_pad + (((size_t)b * HP + (i + 1)) * HP + 1) * CH;
    #pragma unroll
    for (int k = 0; k < 7; ++k) {
        int ch = tid + k * 256;
        int j = ch >> 6;
        int c0 = (ch & 63) << 3;
        *reinterpret_cast<uint4*>(outb + (size_t)j * CH + c0) =
            *reinterpret_cast<const uint4*>(&tile[j * TSTR + c0]);
    }
}

// ------- kernel 3: weight reorder (round-2 proven) ----------
__global__ __launch_bounds__(256) void weight_reorder(
    const float* __restrict__ w, u16* __restrict__ w_r)
{
    __shared__ u16 t[KTOT];
    int oc = blockIdx.x;
    const float* wrow = w + (size_t)oc * KTOT;
    int tid = threadIdx.x;
    #pragma unroll
    for (int k = 0; k < 18; ++k) {
        int idx = tid + k * 256;
        int ic = idx / 9, tap = idx - ic * 9;
        t[tap * 512 + ic] = f2bf(wrow[idx]);
    }
    __syncthreads();
    u16* dst = w_r + (size_t)oc * KTOT;
    #pragma unroll
    for (int k = 0; k < 3; ++k) {
        int ch = tid + k * 256;
        if (ch < 576)
            *reinterpret_cast<uint4*>(dst + ch * 8) =
                *reinterpret_cast<const uint4*>(&t[ch * 8]);
    }
}

// ------- kernel 4: implicit-GEMM conv, M=512 x N=25088 x K=4608 ----------
// 224 blocks (2 mtiles x 112 ntiles), 512 threads = 8 waves, wave tile 64x112
__global__ __launch_bounds__(512, 2) void conv_gemm(
    const u16* __restrict__ w_r, const u16* __restrict__ xr_pad,
    const float* __restrict__ bias, float* __restrict__ out)
{
    __shared__ __align__(16) u16 smem[2][BUFU16];      // 120 KiB
    int p = blockIdx.x;
    int bid = (p & 7) * 28 + (p >> 3);     // XCD x -> bids [28x, 28x+28)
    int mt = bid / 112, nt = bid - mt * 112;
    int m0 = mt * 256;
    int n0 = nt * 224;
    int tid = threadIdx.x;
    int lane = tid & 63;
    int w = tid >> 6;
    int wm = w >> 1, wn = w & 1;

    // staging addresses; swizzle baked into GLOBAL source column, LDS dest linear
    uint32_t aoff[4], boff[4], ldsA[4], ldsB[4];
    bool bmask[4];
    #pragma unroll
    for (int it = 0; it < 4; ++it) {
        int c = tid * 16 + it * 8192;             // byte offset in tile
        int row = c >> 7;                          // 128B rows
        int scol = (c & 127) ^ ((row & 7) << 4);
        aoff[it] = (uint32_t)(m0 + row) * KTOT + (scol >> 1);
        ldsA[it] = c >> 1;
        bmask[it] = (c < BBYTES);                  // wave-uniform (boundary at tid=256)
        int rb = (row < BN) ? row : 0;             // unconditional init (clamped)
        int n = n0 + rb;
        int b2 = n / 784, s2 = n - b2 * 784;
        int oh = s2 / 28, ow = s2 - oh * 28;
        boff[it] = (uint32_t)(((b2 * HP + oh) * HP + ow) * CH) + (scol >> 1);
        ldsB[it] = (ABYTES >> 1) + (uint32_t)((c < BBYTES ? c : 0) >> 1);
    }

    auto stage = [&](int buf, int ks) {
        u16* sA = smem[buf];
        u16* sB = smem[buf] + (ABYTES >> 1);
        int koff = ks * 64;
        int tap = ks >> 3;
        int kh = tap / 3, kw = tap - kh * 3;
        int xoff = (kh * HP + kw) * CH + (ks & 7) * 64;
        #pragma unroll
        for (int it = 0; it < 4; ++it) {
            __builtin_amdgcn_global_load_lds(
                (const __attribute__((address_space(1))) uint32_t*)(w_r + aoff[it] + koff),
                (__attribute__((address_space(3))) uint32_t*)(sA + ldsA[it]),
                16, 0, 0);
        }
        #pragma unroll
        for (int it = 0; it < 4; ++it) {
            if (bmask[it]) {
                __builtin_amdgcn_global_load_lds(
                    (const __attribute__((address_space(1))) uint32_t*)(xr_pad + boff[it] + xoff),
                    (__attribute__((address_space(3))) uint32_t*)(sB + (ldsB[it] - (ABYTES >> 1))),
                    16, 0, 0);
            }
        }
    };

    f32x4 acc[4][7];
    #pragma unroll
    for (int m = 0; m < 4; ++m)
        #pragma unroll
        for (int ni = 0; ni < 7; ++ni)
            acc[m][ni] = (f32x4){0.f, 0.f, 0.f, 0.f};

    int r15 = lane & 15;
    int rq = lane >> 4;
    int xorv = (r15 & 7) << 4;
    int cb0 = ((rq * 16) ^ xorv) >> 1;        // kk=0 swizzled column (u16)
    int cb1 = ((rq * 16 + 64) ^ xorv) >> 1;   // kk=1
    int arow = (wm * 64 + r15) * 64;          // + m*1024
    int brow = (ABYTES >> 1) + (wn * 112 + r15) * 64;   // + ni*1024

    stage(0, 0);
    for (int ks = 0; ks < KSTEPS; ++ks) {
        __syncthreads();                       // drains vmcnt: tile ks ready
        if (ks + 1 < KSTEPS) stage((ks + 1) & 1, ks + 1);
        const u16* sm = smem[ks & 1];
        #pragma unroll
        for (int kk = 0; kk < 2; ++kk) {
            int cb = kk ? cb1 : cb0;
            bf16x8 a[4];
            #pragma unroll
            for (int m = 0; m < 4; ++m)
                a[m] = *reinterpret_cast<const bf16x8*>(sm + arow + m * 1024 + cb);
            #pragma unroll
            for (int ni = 0; ni < 7; ++ni) {
                bf16x8 bv = *reinterpret_cast<const bf16x8*>(sm + brow + ni * 1024 + cb);
                #pragma unroll
                for (int m = 0; m < 4; ++m)
                    acc[m][ni] = __builtin_amdgcn_mfma_f32_16x16x32_bf16(a[m], bv, acc[m][ni], 0, 0, 0);
            }
        }
    }

    // epilogue: D row=(lane>>4)*4+r, col=lane&15
    #pragma unroll
    for (int m = 0; m < 4; ++m) {
        int row = m0 + wm * 64 + m * 16 + rq * 4;
        #pragma unroll
        for (int ni = 0; ni < 7; ++ni) {
            int n = n0 + wn * 112 + ni * 16 + r15;
            int b2 = n / 784, s2 = n - b2 * 784;
            float* op = out + ((size_t)b2 * CH + row) * 784 + s2;
            f32x4 v = acc[m][ni];
            #pragma unroll
            for (int r = 0; r < 4; ++r)
                op[(size_t)r * 784] = v[r] + bias[row + r];
        }
    }
}

extern "C" void kernel_launch(void* const* d_in, const int* in_sizes, int n_in,
                              void* d_out, int out_size, void* d_ws, size_t ws_size,
                              hipStream_t stream)
{
    const float* x    = (const float*)d_in[0];
    const float* wgt  = (const float*)d_in[1];
    const float* bias = (const float*)d_in[2];
    const float* mw   = (const float*)d_in[3];
    const float* filt = (const float*)d_in[4];

    const size_t XR_BYTES = (size_t)NB * HP * HP * CH * 2;   // 29,491,200
    const size_t WR_BYTES = (size_t)CH * KTOT * 2;           //  4,718,592
    u16* xr_pad = (u16*)d_ws;
    u16* w_r    = (u16*)((char*)d_ws + XR_BYTES);
    float* muX  = (float*)((char*)d_ws + XR_BYTES + WR_BYTES);
    float* muY  = (float*)((char*)d_ws + XR_BYTES + WR_BYTES + 65536);

    hipMemsetAsync(xr_pad, 0, XR_BYTES, stream);
    hipLaunchKernelGGL(stats_kernel, dim3(4096), dim3(256), 0, stream, x, muX, muY);
    hipLaunchKernelGGL(mask_relu_transpose, dim3(NB * 28), dim3(256), 0, stream,
                       x, mw, filt, muX, muY, xr_pad);
    hipLaunchKernelGGL(weight_reorder, dim3(512), dim3(256), 0, stream, wgt, w_r);
    hipLaunchKernelGGL(conv_gemm, dim3(224), dim3(512), 0, stream,
                       w_r, xr_pad, bias, (float*)d_out);
}